// Round 7
// baseline (252.296 us; speedup 1.0000x reference)
//
#include <hip/hip_runtime.h>
#include <math.h>

// ProtoLoss: loss = mean_n( -2*sim[n,fam[n]] + logsumexp_f(4*sim[n,f]) )
// sim = (e.p)/(||e||*||p||) -- scale-invariant in p: count division cancels,
// p_hat = raw_sum/||raw_sum||. N=262144, D=128, F=64.
// A) segment raw sums ONLY. Wave-private LDS acc [65][128] (row 64 = dummy
//    for dedup'd slots). 16-row load batches; 4-row subbatches with in-VALU
//    family dedup -> batched ds_reads (no per-row RAW round-trip; round-6
//    counters showed the serialized RMW chain at 1 wave/SIMD cost ~45 us).
// B1) 256-block reduce of 256 partials -> protoRaw fp32
// B2) 1-block normalize -> protoB bf16 (unit norm)
// C) read emb fp32 (L3-resident after A), norms via shfl during staging,
//    f2bf -> LDS, bf16 MFMA 128x64xK128, fused lse; 1 atomic per block.

#define D_DIM 128
#define F_NUM 64
#define AROWS 65                      // 64 fams + dummy row for dedup'd slots
#define AST (AROWS * D_DIM)           // 8320 floats per wave-private acc

typedef __attribute__((ext_vector_type(8))) short short8;
typedef __attribute__((ext_vector_type(4))) float f32x4;

static __device__ __forceinline__ unsigned short f2bf(float x) {
  union { float f; unsigned u; } v; v.f = x;
  unsigned r = v.u + 0x7FFFu + ((v.u >> 16) & 1u);   // RNE
  return (unsigned short)(r >> 16);
}

// ---------------- Pass A -----------------------------------------------------
// grid N/1024 x 256 thr (4 waves = 4 replicas). Full row per wave-instr:
// lane l holds dims 2l,2l+1 (float2, 512B coalesced). 16 loads batched.
// Subbatch-of-4 accumulate: dedup same-family slots (wave-uniform scalar
// compares), then 4 independent ds_read_b64 / adds / ds_write_b64.
__global__ __launch_bounds__(256) void pass_a(
    const float* __restrict__ emb, const int* __restrict__ fam,
    float* __restrict__ psum)
{
  __shared__ float acc[4 * AST];      // 133120 B; wave w owns [w*AST, +AST)
  int t = threadIdx.x;
  float4 z = make_float4(0.f, 0.f, 0.f, 0.f);
  float4* a4 = (float4*)acc;
  for (int i = t; i < AST; i += 256) a4[i] = z;   // 4*AST floats = AST float4s
  __syncthreads();

  int w = t >> 6, l = t & 63;
  float* my = acc + w * AST;
  int base = __builtin_amdgcn_readfirstlane(blockIdx.x * 1024 + w * 256);
  const float2* e2 = (const float2*)emb;

  #pragma unroll 1
  for (int b = 0; b < 16; ++b) {
    float2 v[16]; int f[16];
    #pragma unroll
    for (int j = 0; j < 16; ++j) {            // 16 independent 512B row loads
      int r = base + b * 16 + j;
      v[j] = e2[(size_t)r * 64 + l];
      f[j] = fam[r];                          // uniform -> s_load
    }
    #pragma unroll
    for (int s4 = 0; s4 < 4; ++s4) {
      int jj = s4 * 4;
      // dedup: merge later duplicate slots into the earliest; dead -> row 64
      #pragma unroll
      for (int k = 1; k < 4; ++k) {
        #pragma unroll
        for (int j = 0; j < k; ++j) {
          if (f[jj + j] == f[jj + k]) {       // wave-uniform compare
            v[jj + j].x += v[jj + k].x;
            v[jj + j].y += v[jj + k].y;
            f[jj + k] = 64;                   // dummy row
          }
        }
      }
      float2 cur[4];
      #pragma unroll
      for (int j = 0; j < 4; ++j)             // distinct addrs -> batched reads
        cur[j] = *(float2*)&my[f[jj + j] * D_DIM + 2 * l];
      #pragma unroll
      for (int j = 0; j < 4; ++j) {
        cur[j].x += v[jj + j].x; cur[j].y += v[jj + j].y;
      }
      #pragma unroll
      for (int j = 0; j < 4; ++j)
        *(float2*)&my[f[jj + j] * D_DIM + 2 * l] = cur[j];
    }
  }
  __syncthreads();

  // merge 4 replicas -> block-private psum slot (streaming dwordx4 stores)
  float4* out4 = (float4*)(psum + (size_t)blockIdx.x * (F_NUM * D_DIM));
  #pragma unroll
  for (int k = 0; k < 8; ++k) {
    int idx4 = t + k * 256;                   // 0..2047 float4s of [64][128]
    int ff = idx4 >> 5, c4 = idx4 & 31;
    float4 r = z;
    #pragma unroll
    for (int rp = 0; rp < 4; ++rp) {
      float4 a = *(const float4*)&acc[rp * AST + ff * D_DIM + c4 * 4];
      r.x += a.x; r.y += a.y; r.z += a.z; r.w += a.w;
    }
    out4[idx4] = r;
  }
}

// ---------------- Pass B1 ----------------------------------------------------
// 256 blocks (f x dim-quarter) x 256 thr: reduce nPart partials -> protoRaw.
__global__ __launch_bounds__(256) void pass_b1(
    const float* __restrict__ psum, float* __restrict__ protoRaw, int nPart)
{
  __shared__ float red[256];
  int f = blockIdx.x >> 2, qd = blockIdx.x & 3;
  int t = threadIdx.x;
  int d = qd * 32 + (t & 31), p0 = t >> 5;    // 8 partial-groups
  int per = nPart >> 3;
  float s = 0.f;
  #pragma unroll 8
  for (int i = 0; i < per; ++i)
    s += psum[(size_t)(p0 + 8 * i) * (F_NUM * D_DIM) + f * D_DIM + d];
  red[t] = s;
  __syncthreads();
  if (t < 32) {
    float r = 0.f;
    #pragma unroll
    for (int k = 0; k < 8; ++k) r += red[k * 32 + t];
    protoRaw[f * D_DIM + qd * 32 + t] = r;
  }
}

// ---------------- Pass B2 ----------------------------------------------------
// 1 block x 256 thr: thread (f=t>>2, quarter pt=t&3) -> normalize, bf16.
__global__ __launch_bounds__(256) void pass_b2(
    const float* __restrict__ protoRaw, unsigned short* __restrict__ protoB)
{
  int t = threadIdx.x, f = t >> 2, pt = t & 3;
  const float4* src = (const float4*)(protoRaw + f * D_DIM + pt * 32);
  float4 v[8];
  float n2 = 0.f;
  #pragma unroll
  for (int i = 0; i < 8; ++i) {
    v[i] = src[i];
    n2 += v[i].x * v[i].x + v[i].y * v[i].y + v[i].z * v[i].z + v[i].w * v[i].w;
  }
  n2 += __shfl_xor(n2, 1);                    // quad = same f
  n2 += __shfl_xor(n2, 2);
  float inv = rsqrtf(fmaxf(n2, 1e-24f));      // zero-family -> p_hat=0 -> sim=0
  ushort4* dst = (ushort4*)(protoB + f * D_DIM + pt * 32);
  #pragma unroll
  for (int i = 0; i < 8; ++i) {
    ushort4 u;
    u.x = f2bf(v[i].x * inv); u.y = f2bf(v[i].y * inv);
    u.z = f2bf(v[i].z * inv); u.w = f2bf(v[i].w * inv);
    dst[i] = u;
  }
}

// ---------------- Pass C -----------------------------------------------------
// N/128 blocks x 256 thr. Reads emb fp32 (L3-hot), computes exact fp32 row
// norms via 32-lane shfl during staging, converts to bf16, MFMA 16x16x32
// (128 rows x 64 fams, K=128), fused lse epilogue, 1 atomic per block.
__global__ __launch_bounds__(256) void pass_c(
    const float* __restrict__ emb, const int* __restrict__ fam,
    const unsigned short* __restrict__ protoB,
    float* __restrict__ out, float invN)
{
  __shared__ __align__(16) unsigned short sA[128 * 136];   // 34816 B
  __shared__ __align__(16) unsigned short sB[F_NUM * 136]; // 17408 B
  __shared__ float sInvE[128];
  __shared__ int   sFam[128];
  __shared__ float sWp[4];

  int t = threadIdx.x;
  int R0 = blockIdx.x * 128;
  const float4* src = (const float4*)emb;

  #pragma unroll
  for (int it = 0; it < 16; ++it) {
    int idx = it * 256 + t;                   // 0..4095 float4s
    int row = idx >> 5, c4 = idx & 31;
    float4 v = src[(size_t)(R0 + row) * 32 + c4];
    float nq = v.x * v.x + v.y * v.y + v.z * v.z + v.w * v.w;
    nq += __shfl_xor(nq, 1);  nq += __shfl_xor(nq, 2);  nq += __shfl_xor(nq, 4);
    nq += __shfl_xor(nq, 8);  nq += __shfl_xor(nq, 16);
    if ((t & 31) == 0) sInvE[row] = rsqrtf(fmaxf(nq, 1e-20f));
    ushort4 u;
    u.x = f2bf(v.x); u.y = f2bf(v.y); u.z = f2bf(v.z); u.w = f2bf(v.w);
    *(ushort4*)&sA[row * 136 + (c4 << 2)] = u;
  }
  const ushort4* pb = (const ushort4*)protoB;
  #pragma unroll
  for (int it = 0; it < 4; ++it) {
    int idx = it * 256 + t;                   // 0..1023 ushort4s
    int f = idx >> 4, c4 = idx & 15;          // 16 ushort4 per 64-dim... f=idx>>5
    (void)f; (void)c4;
  }
  #pragma unroll
  for (int it = 0; it < 8; ++it) {
    int idx = it * 256 + t;                   // 0..2047 ushort4s of [64][128]
    int f = idx >> 5, c4 = idx & 31;
    *(ushort4*)&sB[f * 136 + (c4 << 2)] = pb[idx];
  }
  if (t < 128) sFam[t] = fam[R0 + t];
  __syncthreads();

  int w = t >> 6, lane = t & 63, m16 = lane & 15, q = lane >> 4;

  f32x4 acc[2][4] = {};
  const unsigned short* aB0 = &sA[(w * 32 + m16) * 136 + q * 8];
  const unsigned short* aB1 = aB0 + 16 * 136;
  const unsigned short* bB  = &sB[m16 * 136 + q * 8];

  #pragma unroll
  for (int ks = 0; ks < 4; ++ks) {
    int ko = ks * 32;
    short8 a0 = *(const short8*)(aB0 + ko);
    short8 a1 = *(const short8*)(aB1 + ko);
    short8 b0 = *(const short8*)(bB + ko);
    short8 b1 = *(const short8*)(bB + 16 * 136 + ko);
    short8 b2 = *(const short8*)(bB + 32 * 136 + ko);
    short8 b3 = *(const short8*)(bB + 48 * 136 + ko);
    acc[0][0] = __builtin_amdgcn_mfma_f32_16x16x32_bf16(a0, b0, acc[0][0], 0, 0, 0);
    acc[0][1] = __builtin_amdgcn_mfma_f32_16x16x32_bf16(a0, b1, acc[0][1], 0, 0, 0);
    acc[0][2] = __builtin_amdgcn_mfma_f32_16x16x32_bf16(a0, b2, acc[0][2], 0, 0, 0);
    acc[0][3] = __builtin_amdgcn_mfma_f32_16x16x32_bf16(a0, b3, acc[0][3], 0, 0, 0);
    acc[1][0] = __builtin_amdgcn_mfma_f32_16x16x32_bf16(a1, b0, acc[1][0], 0, 0, 0);
    acc[1][1] = __builtin_amdgcn_mfma_f32_16x16x32_bf16(a1, b1, acc[1][1], 0, 0, 0);
    acc[1][2] = __builtin_amdgcn_mfma_f32_16x16x32_bf16(a1, b2, acc[1][2], 0, 0, 0);
    acc[1][3] = __builtin_amdgcn_mfma_f32_16x16x32_bf16(a1, b3, acc[1][3], 0, 0, 0);
  }

  // epilogue: sim = acc * invE (protos unit-norm).
  // D[row= w*32+rt*16+q*4+i][col= ft*16+m16] = acc[rt][ft][i]
  float wp = 0.f;
  #pragma unroll
  for (int rt = 0; rt < 2; ++rt) {
    #pragma unroll
    for (int i = 0; i < 4; ++i) {
      int row = w * 32 + rt * 16 + q * 4 + i;
      float inv_e = sInvE[row];
      int fr = sFam[row], frh = fr >> 4, frl = fr & 15;
      float es = 0.f, ps = 0.f;
      #pragma unroll
      for (int ft = 0; ft < 4; ++ft) {
        float sim = acc[rt][ft][i] * inv_e;
        es += __expf(4.f * sim - 4.f);        // sim in [-1,1] -> arg in [-8,0]
        if (frl == m16 && frh == ft) ps = sim;
      }
      #pragma unroll
      for (int off = 1; off < 16; off <<= 1) {
        es += __shfl_xor(es, off);
        ps += __shfl_xor(ps, off);
      }
      if (m16 == 0) wp += 4.f + __logf(es) - 2.f * ps;
    }
  }
  wp += __shfl_xor(wp, 16);
  wp += __shfl_xor(wp, 32);
  if (lane == 0) sWp[w] = wp;
  __syncthreads();
  if (t == 0)
    unsafeAtomicAdd(out, (sWp[0] + sWp[1] + sWp[2] + sWp[3]) * invN);
}

extern "C" void kernel_launch(void* const* d_in, const int* in_sizes, int n_in,
                              void* d_out, int out_size, void* d_ws, size_t ws_size,
                              hipStream_t stream) {
  const float* emb = (const float*)d_in[0];
  const int* fam = (const int*)d_in[1];
  int N = in_sizes[0] / D_DIM;               // 262144
  int blocksA = N / 1024;                    // 256
  int blocksC = N / 128;                     // 2048

  // ws (float units): psum[256*8192] | protoRaw[8192] | protoB(8192 ushort)
  float* ws = (float*)d_ws;
  float* psum = ws;
  size_t off = (size_t)blocksA * (F_NUM * D_DIM);
  float* protoRaw = ws + off;                off += F_NUM * D_DIM;
  unsigned short* protoB = (unsigned short*)(ws + off);

  (void)hipMemsetAsync(d_out, 0, sizeof(float), stream);
  pass_a<<<blocksA, 256, 0, stream>>>(emb, fam, psum);
  pass_b1<<<4 * F_NUM, 256, 0, stream>>>(psum, protoRaw, blocksA);
  pass_b2<<<1, 256, 0, stream>>>(protoRaw, protoB);
  pass_c<<<blocksC, 256, 0, stream>>>(emb, fam, protoB,
                                      (float*)d_out, 1.0f / (float)N);
}